// Round 1
// baseline (686.253 us; speedup 1.0000x reference)
//
#include <hip/hip_runtime.h>

// Segment-sum: out[idx[e], d] += H[e, d]  for e in [0,E), d in [0,64)
// One thread per (edge, quad-of-4-floats): float4 load + 4 atomicAdds.
__global__ void AggrSum_scatter(const float* __restrict__ H,
                                const int* __restrict__ idx,
                                float* __restrict__ out,
                                int E) {
    const int t = blockIdx.x * blockDim.x + threadIdx.x;
    const int quads = E * 16;              // 64 floats/row = 16 float4 per row
    if (t >= quads) return;
    const int e = t >> 4;                  // edge
    const int q = t & 15;                  // which float4 within the row
    const int node = idx[e];
    const float4 v = reinterpret_cast<const float4*>(H)[(size_t)t];
    float* o = out + (size_t)node * 64 + (size_t)q * 4;
    atomicAdd(o + 0, v.x);
    atomicAdd(o + 1, v.y);
    atomicAdd(o + 2, v.z);
    atomicAdd(o + 3, v.w);
}

extern "C" void kernel_launch(void* const* d_in, const int* in_sizes, int n_in,
                              void* d_out, int out_size, void* d_ws, size_t ws_size,
                              hipStream_t stream) {
    const float* H   = (const float*)d_in[0];
    const int*   idx = (const int*)d_in[1];
    float*       out = (float*)d_out;
    const int E = in_sizes[1];             // 800000 edges

    // Output must be zeroed every call (we accumulate into it; harness does
    // not re-poison/zero between replays).
    hipMemsetAsync(d_out, 0, (size_t)out_size * sizeof(float), stream);

    const int quads = E * 16;
    const int block = 256;
    const int grid = (quads + block - 1) / block;
    AggrSum_scatter<<<grid, block, 0, stream>>>(H, idx, out, E);
}

// Round 2
// 122.174 us; speedup vs baseline: 5.6170x; 5.6170x over previous
//
#include <hip/hip_runtime.h>

// Segment-sum via on-device bucketing (scatter->gather inversion).
//   ws layout: [ cnt: N int ][ bucket: N*CAP int ]
// CAP=64 slots/node; avg load 16 (Poisson) -> overflow prob ~1e-14, but a
// correct atomic fallback handles slot>=CAP anyway.
#define CAP 64

// ---- fallback: direct atomic scatter (used only if ws_size too small) ----
__global__ void AggrSum_scatter(const float* __restrict__ H,
                                const int* __restrict__ idx,
                                float* __restrict__ out,
                                int E) {
    const int t = blockIdx.x * blockDim.x + threadIdx.x;
    const int quads = E * 16;
    if (t >= quads) return;
    const int e = t >> 4;
    const int q = t & 15;
    const int node = idx[e];
    const float4 v = reinterpret_cast<const float4*>(H)[(size_t)t];
    float* o = out + (size_t)node * 64 + (size_t)q * 4;
    atomicAdd(o + 0, v.x);
    atomicAdd(o + 1, v.y);
    atomicAdd(o + 2, v.z);
    atomicAdd(o + 3, v.w);
}

// ---- pass 1: bucket fill. One int atomic per edge. ----
__global__ void AggrSum_fill(const int* __restrict__ idx,
                             const float* __restrict__ H,
                             int* __restrict__ cnt,
                             int* __restrict__ bucket,
                             float* __restrict__ out,
                             int E) {
    const int e = blockIdx.x * blockDim.x + threadIdx.x;
    if (e >= E) return;
    const int n = idx[e];
    const int slot = atomicAdd(&cnt[n], 1);
    if (slot < CAP) {
        bucket[(size_t)n * CAP + slot] = e;
    } else {
        // overflow (practically never): add this row directly into out
        const float* h = H + (size_t)e * 64;
        float* o = out + (size_t)n * 64;
        for (int d = 0; d < 64; ++d) atomicAdd(o + d, h[d]);
    }
}

// ---- pass 2: per-node gather. One wave (64 lanes) per node, lane = dim. ----
__global__ void AggrSum_gather(const float* __restrict__ H,
                               const int* __restrict__ cnt,
                               const int* __restrict__ bucket,
                               float* __restrict__ out,
                               int N) {
    const int lane = threadIdx.x & 63;
    const int wv   = threadIdx.x >> 6;
    const int n    = blockIdx.x * 4 + wv;       // 256 threads = 4 waves/block
    if (n >= N) return;
    const int c  = cnt[n];
    const int cc = c < CAP ? c : CAP;
    // lane i holds bucket entry i (one coalesced 256B read per wave)
    const int myid = bucket[(size_t)n * CAP + lane];
    float acc = 0.0f;
    for (int i = 0; i < cc; ++i) {
        const int e = __shfl(myid, i);          // broadcast entry i to all lanes
        acc += H[(size_t)e * 64 + lane];        // coalesced 256B row read
    }
    float* o = out + (size_t)n * 64 + lane;
    if (c > CAP) acc += *o;                     // merge overflow contributions
    *o = acc;
}

extern "C" void kernel_launch(void* const* d_in, const int* in_sizes, int n_in,
                              void* d_out, int out_size, void* d_ws, size_t ws_size,
                              hipStream_t stream) {
    const float* H   = (const float*)d_in[0];
    const int*   idx = (const int*)d_in[1];
    float*       out = (float*)d_out;
    const int E = in_sizes[1];                  // 800000
    const int D = in_sizes[0] / E;              // 64
    const int N = out_size / D;                 // 50000

    const size_t need = (size_t)N * sizeof(int) + (size_t)N * CAP * sizeof(int);

    if (ws_size < need) {
        // fallback: atomic scatter
        hipMemsetAsync(d_out, 0, (size_t)out_size * sizeof(float), stream);
        const int quads = E * 16;
        AggrSum_scatter<<<(quads + 255) / 256, 256, 0, stream>>>(H, idx, out, E);
        return;
    }

    int* cnt    = (int*)d_ws;
    int* bucket = cnt + N;

    // zero cnt every call; zero out for the overflow-atomic path
    hipMemsetAsync(cnt, 0, (size_t)N * sizeof(int), stream);
    hipMemsetAsync(d_out, 0, (size_t)out_size * sizeof(float), stream);

    AggrSum_fill<<<(E + 255) / 256, 256, 0, stream>>>(idx, H, cnt, bucket, out, E);

    const int nodes_per_block = 4;              // 256 threads = 4 waves
    AggrSum_gather<<<(N + nodes_per_block - 1) / nodes_per_block, 256, 0, stream>>>(
        H, cnt, bucket, out, N);
}

// Round 3
// 101.463 us; speedup vs baseline: 6.7636x; 1.2041x over previous
//
#include <hip/hip_runtime.h>

// Segment-sum via on-device bucketing (scatter->gather inversion).
//   ws layout: [ cnt: N int ][ bucket: N*CAP int ]
// CAP=64 slots/node; avg load 16 (Poisson) -> overflow prob ~1e-14, but a
// correct atomic fallback handles slot>=CAP anyway.
//
// Gather v2: 4 lane-groups x float4 -> 4 rows per load instruction, 8 rows
// per iteration (2KB in flight per wave) to break the per-iteration
// vmcnt(0) latency serialization seen in v1 (118us @ ~2TB/s).
#define CAP 64

// ---- fallback: direct atomic scatter (used only if ws_size too small) ----
__global__ void AggrSum_scatter(const float* __restrict__ H,
                                const int* __restrict__ idx,
                                float* __restrict__ out,
                                int E) {
    const int t = blockIdx.x * blockDim.x + threadIdx.x;
    const int quads = E * 16;
    if (t >= quads) return;
    const int e = t >> 4;
    const int q = t & 15;
    const int node = idx[e];
    const float4 v = reinterpret_cast<const float4*>(H)[(size_t)t];
    float* o = out + (size_t)node * 64 + (size_t)q * 4;
    atomicAdd(o + 0, v.x);
    atomicAdd(o + 1, v.y);
    atomicAdd(o + 2, v.z);
    atomicAdd(o + 3, v.w);
}

// ---- pass 1: bucket fill. One int atomic per edge. ----
__global__ void AggrSum_fill(const int* __restrict__ idx,
                             const float* __restrict__ H,
                             int* __restrict__ cnt,
                             int* __restrict__ bucket,
                             float* __restrict__ out,
                             int E) {
    const int e = blockIdx.x * blockDim.x + threadIdx.x;
    if (e >= E) return;
    const int n = idx[e];
    const int slot = atomicAdd(&cnt[n], 1);
    if (slot < CAP) {
        bucket[(size_t)n * CAP + slot] = e;
    } else {
        // overflow (practically never): add this row directly into out
        const float* h = H + (size_t)e * 64;
        float* o = out + (size_t)n * 64;
        for (int d = 0; d < 64; ++d) atomicAdd(o + d, h[d]);
    }
}

// ---- pass 2: per-node gather, high-MLP version. One wave per node. ----
// lane = (g, q): g = lane>>4 (edge sub-index group), q = lane&15 (float4 slot).
// Iteration i: group g loads rows of bucket entries 8i+g and 8i+4+g as float4.
// Cross-group reduce via shfl_xor(16,32); lanes 0..15 store one float4 each.
__global__ void AggrSum_gather(const float* __restrict__ H,
                               const int* __restrict__ cnt,
                               const int* __restrict__ bucket,
                               float* __restrict__ out,
                               int N) {
    const int lane = threadIdx.x & 63;
    const int wv   = threadIdx.x >> 6;
    const int n    = blockIdx.x * 4 + wv;       // 256 threads = 4 waves/block
    if (n >= N) return;
    const int c  = cnt[n];
    const int cc = c < CAP ? c : CAP;
    // lane i holds bucket entry i (one coalesced 256B read per wave)
    const int myid = bucket[(size_t)n * CAP + lane];
    const int g = lane >> 4;
    const int q = lane & 15;

    float4 acc = make_float4(0.f, 0.f, 0.f, 0.f);
    for (int i = 0; i < cc; i += 8) {
        const int j0 = i + g;
        const int j1 = i + 4 + g;
        const int e0 = __shfl(myid, j0);
        const int e1 = __shfl(myid, j1);
        float4 v0 = make_float4(0.f, 0.f, 0.f, 0.f);
        float4 v1 = make_float4(0.f, 0.f, 0.f, 0.f);
        // predicated: bucket slots >= cc hold garbage (poisoned ws)
        if (j0 < cc) v0 = reinterpret_cast<const float4*>(H + (size_t)e0 * 64)[q];
        if (j1 < cc) v1 = reinterpret_cast<const float4*>(H + (size_t)e1 * 64)[q];
        acc.x += v0.x + v1.x;
        acc.y += v0.y + v1.y;
        acc.z += v0.z + v1.z;
        acc.w += v0.w + v1.w;
    }

    // reduce the 4 groups (lanes l, l^16, l^32, l^48 hold partials of slot q)
    acc.x += __shfl_xor(acc.x, 16); acc.y += __shfl_xor(acc.y, 16);
    acc.z += __shfl_xor(acc.z, 16); acc.w += __shfl_xor(acc.w, 16);
    acc.x += __shfl_xor(acc.x, 32); acc.y += __shfl_xor(acc.y, 32);
    acc.z += __shfl_xor(acc.z, 32); acc.w += __shfl_xor(acc.w, 32);

    if (g == 0) {
        float4* o = reinterpret_cast<float4*>(out + (size_t)n * 64) + q;
        if (c > CAP) {                          // merge overflow contributions
            float4 prev = *o;
            acc.x += prev.x; acc.y += prev.y; acc.z += prev.z; acc.w += prev.w;
        }
        *o = acc;
    }
}

extern "C" void kernel_launch(void* const* d_in, const int* in_sizes, int n_in,
                              void* d_out, int out_size, void* d_ws, size_t ws_size,
                              hipStream_t stream) {
    const float* H   = (const float*)d_in[0];
    const int*   idx = (const int*)d_in[1];
    float*       out = (float*)d_out;
    const int E = in_sizes[1];                  // 800000
    const int D = in_sizes[0] / E;              // 64
    const int N = out_size / D;                 // 50000

    const size_t need = (size_t)N * sizeof(int) + (size_t)N * CAP * sizeof(int);

    if (ws_size < need) {
        // fallback: atomic scatter
        hipMemsetAsync(d_out, 0, (size_t)out_size * sizeof(float), stream);
        const int quads = E * 16;
        AggrSum_scatter<<<(quads + 255) / 256, 256, 0, stream>>>(H, idx, out, E);
        return;
    }

    int* cnt    = (int*)d_ws;
    int* bucket = cnt + N;

    // zero cnt every call; zero out for the (never-taken) overflow-atomic path
    hipMemsetAsync(cnt, 0, (size_t)N * sizeof(int), stream);
    hipMemsetAsync(d_out, 0, (size_t)out_size * sizeof(float), stream);

    AggrSum_fill<<<(E + 255) / 256, 256, 0, stream>>>(idx, H, cnt, bucket, out, E);

    const int nodes_per_block = 4;              // 256 threads = 4 waves
    AggrSum_gather<<<(N + nodes_per_block - 1) / nodes_per_block, 256, 0, stream>>>(
        H, cnt, bucket, out, N);
}